// Round 4
// baseline (94.192 us; speedup 1.0000x reference)
//
#include <hip/hip_runtime.h>
#include <hip/hip_bf16.h>
#include <stdint.h>

// CapsNet routing with size-1 softmax axis: cj == 1, so the op collapses to
//   s[b][c] = sum_t In[b][t] * W2[t][c]   b<64, t<16384 (=i*8+k), c<512 (=j*16+l)
//   out[b][c] = squash over l (groups of 16)
// W2[t][c] in W[I][J][K][L]: i*4096 + j*128 + k*16 + l.
// Verified fragment layouts (m91/m92), unchanged from the round-3 PASS:
//   A[row][k]: row=lane&15, k=(lane>>4)*8+e ; B[k][col]: col=lane&15, same k
//   D[row][col]: col=lane&15, row=(lane>>4)*4+reg
// fp32 accuracy via hi/lo bf16 split (3 MFMAs). This round: W staged through
// LDS with global_load_lds width=16 (4 coalesced issues/lane/step instead of
// 16 scalar dwords), In register-double-buffered, finish with ILP-8 reduce.

using f32x4 = __attribute__((ext_vector_type(4))) float;
using s16x8 = __attribute__((ext_vector_type(8))) short;

typedef __attribute__((address_space(3))) uint32_t lds_u32;
typedef const __attribute__((address_space(1))) uint32_t glb_u32;

__device__ __forceinline__ short f2bf(float x) {
    __hip_bfloat16 h = __float2bfloat16(x);   // RNE
    return *reinterpret_cast<short*>(&h);
}
__device__ __forceinline__ float bf2f(short s) {
    return __uint_as_float(((uint32_t)(uint16_t)s) << 16);
}

struct IBuf { f32x4 v[4][2]; };   // [mtile][half]: In[mt*16+cin][kb+q*8 ..+7]

template<int KSPLITS>
__global__ __launch_bounds__(256)
void caps_gemm(const float* __restrict__ In, const float* __restrict__ W,
               float* __restrict__ ws)
{
    constexpr int KS    = 16384 / KSPLITS;  // t-extent per block
    constexpr int NSTEP = KS / 32;          // >=2 and even for all tiers

    const int tid  = threadIdx.x;
    const int wv   = tid >> 6;
    const int lane = tid & 63;
    const int q    = lane >> 4;
    const int cin  = lane & 15;
    const int kb0  = blockIdx.x * KS;
    const int j0   = blockIdx.y * 8;              // block c-range = [j0*16, j0*16+128)
    const int c0   = blockIdx.y * 128 + wv * 32;  // wave's first column

    // W tile per step: [4 i][8 jj][8 k][16 l] fp32 = 16 KB.
    // LDS float index: i*1024 + jj*128 + k*16 + l  (linear in lane order below)
    __shared__ float wlds[2][4096];

    // staging decomposition of tid: jj=tid>>5, k=(tid>>2)&7, l4=tid&3 (16B chunk)
    const int s_jj = tid >> 5, s_k = (tid >> 2) & 7, s_l4 = tid & 3;
    const float* wsrc0 = W + (size_t)(j0 + s_jj) * 128 + s_k * 16 + s_l4 * 4;

    f32x4 acc[4][2] = {};   // [mtile][ntile]

    auto stage_w = [&](int s, int b) {
        const int i0s = (kb0 >> 3) + s * 4;
        #pragma unroll
        for (int n = 0; n < 4; ++n) {           // n == i_local
            const float* gp = wsrc0 + (size_t)(i0s + n) * 4096;
            // wave-uniform LDS base; HW adds lane*16B -> chunk tid lands at
            // float offset n*1024 + tid*4  == i*1024 + jj*128 + k*16 + l4*4
            float* lp = &wlds[b][n * 1024 + wv * 256];
            __builtin_amdgcn_global_load_lds((glb_u32*)gp, (lds_u32*)lp, 16, 0, 0);
        }
    };

    auto load_in = [&](int s, IBuf& ib) {
        const int kb = kb0 + s * 32;
        #pragma unroll
        for (int mt = 0; mt < 4; ++mt) {
            const float* ip = In + (size_t)(mt * 16 + cin) * 16384 + kb + q * 8;
            ib.v[mt][0] = *(const f32x4*)(ip);
            ib.v[mt][1] = *(const f32x4*)(ip + 4);
        }
    };

    auto compute = [&](int b, const IBuf& ib) {
        s16x8 Bh[2], Bl[2];
        #pragma unroll
        for (int nt = 0; nt < 2; ++nt) {
            const int jjf = wv * 2 + nt;        // wave's local jj for this n-tile
            #pragma unroll
            for (int e = 0; e < 8; ++e) {       // k = e for i_local = q
                float x = wlds[b][q * 1024 + jjf * 128 + e * 16 + cin];
                short h = f2bf(x);
                Bh[nt][e] = h;
                Bl[nt][e] = f2bf(x - bf2f(h));
            }
        }
        s16x8 Ah[4], Al[4];
        #pragma unroll
        for (int mt = 0; mt < 4; ++mt)
            #pragma unroll
            for (int e = 0; e < 8; ++e) {
                float x = ib.v[mt][e >> 2][e & 3];
                short h = f2bf(x);
                Ah[mt][e] = h;
                Al[mt][e] = f2bf(x - bf2f(h));
            }
        #pragma unroll
        for (int mt = 0; mt < 4; ++mt)
            #pragma unroll
            for (int nt = 0; nt < 2; ++nt) {
                acc[mt][nt] = __builtin_amdgcn_mfma_f32_16x16x32_bf16(Ah[mt], Bh[nt], acc[mt][nt], 0, 0, 0);
                acc[mt][nt] = __builtin_amdgcn_mfma_f32_16x16x32_bf16(Al[mt], Bh[nt], acc[mt][nt], 0, 0, 0);
                acc[mt][nt] = __builtin_amdgcn_mfma_f32_16x16x32_bf16(Ah[mt], Bl[nt], acc[mt][nt], 0, 0, 0);
            }
    };

    IBuf iA, iB;
    stage_w(0, 0);
    load_in(0, iA);
    __syncthreads();                            // drains global_load_lds (vmcnt) too
    #pragma unroll 1
    for (int ss = 0; ss < NSTEP; ss += 2) {
        if (ss + 1 < NSTEP) { stage_w(ss + 1, 1); load_in(ss + 1, iB); }
        compute(0, iA);
        __syncthreads();                        // buf1 staged; buf0 reads done
        if (ss + 2 < NSTEP) { stage_w(ss + 2, 0); load_in(ss + 2, iA); }
        if (ss + 1 < NSTEP) compute(1, iB);
        __syncthreads();                        // buf0 staged; buf1 reads done
    }

    // D tile (mt,nt): row b = mt*16 + q*4 + r, col c = c0 + nt*16 + cin
    float* wsb = ws + (size_t)blockIdx.x * 32768;   // [b][c] slab per k-split
    #pragma unroll
    for (int mt = 0; mt < 4; ++mt)
        #pragma unroll
        for (int nt = 0; nt < 2; ++nt) {
            const int c = c0 + nt * 16 + cin;
            #pragma unroll
            for (int r = 0; r < 4; ++r)
                wsb[(mt * 16 + q * 4 + r) * 512 + c] = acc[mt][nt][r];
        }
}

__global__ __launch_bounds__(256)
void caps_finish(const float* __restrict__ ws, float* __restrict__ out, int nk)
{
    const int o = blockIdx.x * 256 + threadIdx.x;   // o = b*512 + j*16 + l
    float s = 0.0f;
    if (nk >= 8) {
        float a[8] = {};
        #pragma unroll 1
        for (int ks = 0; ks < nk; ks += 8)
            #pragma unroll
            for (int u = 0; u < 8; ++u)
                a[u] += ws[(size_t)(ks + u) * 32768 + o];
        #pragma unroll
        for (int u = 0; u < 8; ++u) s += a[u];
    } else {
        for (int ks = 0; ks < nk; ++ks) s += ws[(size_t)ks * 32768 + o];
    }
    float s2 = s * s;                                // sum s^2 over l (16 lanes)
    s2 += __shfl_xor(s2, 1);
    s2 += __shfl_xor(s2, 2);
    s2 += __shfl_xor(s2, 4);
    s2 += __shfl_xor(s2, 8);
    const float scale = s2 / (1.0f + s2);
    out[o] = s * scale / sqrtf(s2 + 1e-7f);
}

extern "C" void kernel_launch(void* const* d_in, const int* in_sizes, int n_in,
                              void* d_out, int out_size, void* d_ws, size_t ws_size,
                              hipStream_t stream)
{
    (void)in_sizes; (void)n_in; (void)out_size;
    const float* In = (const float*)d_in[0];   // [64][2048][8]
    const float* W  = (const float*)d_in[1];   // [2048][32][8][16]
    float* out = (float*)d_out;                // 32768 floats
    float* ws  = (float*)d_ws;

    const size_t slab = 32768u * sizeof(float);     // one k-split partial: 128 KiB
    if (ws_size >= 128 * slab) {
        // 512 blocks -> 2 blocks/CU
        caps_gemm<128><<<dim3(128, 4), dim3(256), 0, stream>>>(In, W, ws);
        caps_finish<<<dim3(128), dim3(256), 0, stream>>>(ws, out, 128);
    } else if (ws_size >= 64 * slab) {
        caps_gemm<64><<<dim3(64, 4), dim3(256), 0, stream>>>(In, W, ws);
        caps_finish<<<dim3(128), dim3(256), 0, stream>>>(ws, out, 64);
    } else if (ws_size >= 8 * slab) {
        caps_gemm<8><<<dim3(8, 4), dim3(256), 0, stream>>>(In, W, ws);
        caps_finish<<<dim3(128), dim3(256), 0, stream>>>(ws, out, 8);
    } else {
        // fallback: d_out holds the single partial (in-place safe: each finish
        // thread reads only its own element before writing it)
        caps_gemm<1><<<dim3(1, 4), dim3(256), 0, stream>>>(In, W, out);
        caps_finish<<<dim3(128), dim3(256), 0, stream>>>(out, out, 1);
    }
}